// Round 12
// baseline (284.973 us; speedup 1.0000x reference)
//
#include <hip/hip_runtime.h>
#include <math.h>

// SoftPeakAwareLoss on MI355X — R10 resubmit (R10 bench hit GPU-acquisition
// timeout, never measured): linear-coalesced LDS staging at high occupancy.
// R0-R8 invariant (~105-117us, ~2.5 TB/s demand, waves idle ~95%) indicts
// TA/L1 address processing of divergent-span loads (12-24 lines per
// wave-load). R10 stages 64-day tiles with PURE-LINEAR float4 loads (8 lines
// per wave-load, m13 pattern), LDS only 21.5 KB/block -> 6 blocks/CU = 24
// waves resident, single-buffered, inter-block desync pipelines stage vs
// compute. Compute = validated R7/R8 seg_body (absmax 0.0) reading LDS
// (day-stride 28 floats: float4-aligned, 2-way banks = free).

#define HOURS_ 24
#define WIN_ 2
#define NEGV (-1e9f)
#define DPB 64     // days per tile
#define DSTR 28    // padded day stride in floats (float4-aligned, bank-spread)
#define CH_PER_ARR (DPB * 6)      // 384 float4 chunks per array per tile
#define CH_TOTAL (CH_PER_ARR * 3) // 1152

__device__ __forceinline__ float frcp(float x) { return __builtin_amdgcn_rcpf(x); }

#define DPP_XOR1 0xB1   // quad_perm [1,0,3,2]
#define DPP_XOR2 0x4E   // quad_perm [2,3,0,1]

template<int CTRL>
__device__ __forceinline__ int dpp_i(int src) {
    return __builtin_amdgcn_update_dpp(0, src, CTRL, 0xF, 0xF, true);
}
template<int CTRL>
__device__ __forceinline__ float dpp_f(float x) {
    return __int_as_float(dpp_i<CTRL>(__float_as_int(x)));
}

// One 6-hour segment of one day, inputs read from LDS; lanes (l&3)==0..3 own
// segments 0..3 and combine via DPP quad butterflies. Math identical to
// R7/R8 (validated absmax 0.0).
__device__ __forceinline__ void seg_body_lds(
    const float* __restrict__ ap, const float* __restrict__ bp,
    const float* __restrict__ mp,
    int seg, float vfl,
    float& o, float& mg, float& tl, float& sh)
{
    const int h0 = seg * 6;
    float a[6], b[6], dm[6];
    #pragma unroll
    for (int k = 0; k < 6; ++k) { a[k] = ap[h0 + k]; b[k] = bp[h0 + k]; dm[k] = mp[h0 + k]; }

    // ---- L_overall partial (own hours only)
    float oo = 0.f;
    #pragma unroll
    for (int k = 0; k < 6; ++k) { float d = a[k] - b[k]; oo = fmaf(d, d, oo); }
    o = fmaf(oo, vfl, o);

    // ---- masked values
    float bm[6], am[6];
    #pragma unroll
    for (int k = 0; k < 6; ++k) {
        bool dy = dm[k] > 0.5f;
        bm[k] = dy ? b[k] : NEGV;
        am[k] = dy ? a[k] : NEGV;
    }

    // ---- local first-occurrence argmax over 6 (ordered tree, strict >)
    bool  s0 = bm[1] > bm[0]; float v01 = s0 ? bm[1] : bm[0]; int i01 = s0 ? h0+1 : h0;
    bool  s1 = bm[3] > bm[2]; float v23 = s1 ? bm[3] : bm[2]; int i23 = s1 ? h0+3 : h0+2;
    bool  s2 = bm[5] > bm[4]; float v45 = s2 ? bm[5] : bm[4]; int i45 = s2 ? h0+5 : h0+4;
    bool  tA = v23 > v01; float mt = tA ? v23 : v01; int pk = tA ? i23 : i01;
    bool  tB = v45 > mt;  mt = tB ? v45 : mt;        pk = tB ? i45 : pk;
    float mp2 = fmaxf(fmaxf(fmaxf(am[0], am[1]), fmaxf(am[2], am[3])),
                      fmaxf(am[4], am[5]));

    // ---- quad butterfly (VALU-speed DPP; ties -> lower hour)
    {
        float mt_o = dpp_f<DPP_XOR1>(mt); int pk_o = dpp_i<DPP_XOR1>(pk);
        float mp_o = dpp_f<DPP_XOR1>(mp2);
        bool to = (mt_o > mt) || (mt_o == mt && pk_o < pk);
        pk = to ? pk_o : pk; mt = fmaxf(mt, mt_o); mp2 = fmaxf(mp2, mp_o);
        mt_o = dpp_f<DPP_XOR2>(mt); pk_o = dpp_i<DPP_XOR2>(pk);
        mp_o = dpp_f<DPP_XOR2>(mp2);
        to = (mt_o > mt) || (mt_o == mt && pk_o < pk);
        pk = to ? pk_o : pk; mt = fmaxf(mt, mt_o); mp2 = fmaxf(mp2, mp_o);
    }

    // ---- soft peaks: exp((x-m)*10); night -> exp(-1e10)=0
    float mt10 = mt * 10.f, mp10 = mp2 * 10.f;
    float set = 0.f, syt = 0.f, sht = 0.f;
    float sep = 0.f, syp = 0.f, shp = 0.f;
    #pragma unroll
    for (int k = 0; k < 6; ++k) {
        float et = __expf(fmaf(bm[k], 10.f, -mt10));
        float ep = __expf(fmaf(am[k], 10.f, -mp10));
        float hh = (float)(h0 + k);
        set += et; syt = fmaf(et, b[k], syt); sht = fmaf(et, hh, sht);
        sep += ep; syp = fmaf(ep, a[k], syp); shp = fmaf(ep, hh, shp);
    }
    set += dpp_f<DPP_XOR1>(set); set += dpp_f<DPP_XOR2>(set);
    syt += dpp_f<DPP_XOR1>(syt); syt += dpp_f<DPP_XOR2>(syt);
    sht += dpp_f<DPP_XOR1>(sht); sht += dpp_f<DPP_XOR2>(sht);
    sep += dpp_f<DPP_XOR1>(sep); sep += dpp_f<DPP_XOR2>(sep);
    syp += dpp_f<DPP_XOR1>(syp); syp += dpp_f<DPP_XOR2>(syp);
    shp += dpp_f<DPP_XOR1>(shp); shp += dpp_f<DPP_XOR2>(shp);
    {
        float rs = frcp(set), rq = frcp(sep);
        float d1 = syp * rq - syt * rs;
        float d2 = shp * rq - sht * rs;
        float once = (seg == 0) ? vfl : 0.f;   // count each day once
        mg = fmaf(d1 * d1, once, mg);
        tl = fmaf(d2 * d2, once, tl);
    }

    // ---- shape loss: window [pk-2, pk+2] clipped; analytic exact 1/cnt
    int lo = pk - WIN_; lo = lo < 0 ? 0 : lo;
    int hi = pk + WIN_; hi = hi > 23 ? 23 : hi;
    int cnt = hi - lo + 1;                      // 3,4,5
    float invcnt = (cnt == 5) ? 0.2f : ((cnt == 4) ? 0.25f : (1.f / 3.f));
    float twm = -INFINITY, pwm = -INFINITY;
    #pragma unroll
    for (int k = 0; k < 6; ++k) {
        int hg = h0 + k;
        bool in = (hg >= lo) && (hg <= hi);
        twm = in ? fmaxf(twm, b[k]) : twm;
        pwm = in ? fmaxf(pwm, a[k]) : pwm;
    }
    twm = fmaxf(twm, dpp_f<DPP_XOR1>(twm)); twm = fmaxf(twm, dpp_f<DPP_XOR2>(twm));
    pwm = fmaxf(pwm, dpp_f<DPP_XOR1>(pwm)); pwm = fmaxf(pwm, dpp_f<DPP_XOR2>(pwm));
    {
        float rt = frcp(twm + 1e-6f);
        float rp = frcp(pwm + 1e-6f);
        float ss = 0.f;
        #pragma unroll
        for (int k = 0; k < 6; ++k) {
            int hg = h0 + k;
            bool in = (hg >= lo) && (hg <= hi);
            float d = fmaf(a[k], rp, -(b[k] * rt));
            ss = in ? fmaf(d, d, ss) : ss;
        }
        sh = fmaf(ss * invcnt, vfl, sh);
    }
}

__global__ __launch_bounds__(256) void splloss_days(
    const float* __restrict__ ypred,
    const float* __restrict__ ytrue,
    const float* __restrict__ isday,
    float4* __restrict__ partials,
    int n_days, int ntiles)
{
    __shared__ float lds[3][DPB][DSTR];   // 21504 B -> 6-7 blocks/CU

    const int tid   = threadIdx.x;
    const int seg   = tid & 3;            // 6-hour segment within the day
    const int dslot = tid >> 2;           // day slot within tile: 0..63

    float o = 0.f, mg = 0.f, tl = 0.f, sh = 0.f;

    for (int t = blockIdx.x; t < ntiles; t += gridDim.x) {
        const size_t baseDay = (size_t)t * DPB;

        // ---- stage tile: pure-linear coalesced float4 loads (m13 pattern)
        #pragma unroll
        for (int j = 0; j < 5; ++j) {
            int c = tid + j * 256;
            if (c < CH_TOTAL) {
                int arr = c / CH_PER_ARR;
                int rem = c - arr * CH_PER_ARR;
                int day = rem / 6;
                int h0  = (rem - day * 6) * 4;
                const float* g = (arr == 0) ? ypred : (arr == 1) ? ytrue : isday;
                size_t gd = baseDay + (size_t)day;
                float4 v = make_float4(0.f, 0.f, 0.f, 0.f);
                if (gd < (size_t)n_days)
                    v = *reinterpret_cast<const float4*>(g + gd * 24 + h0);
                *reinterpret_cast<float4*>(&lds[arr][day][h0]) = v;
            }
        }
        __syncthreads();

        // ---- compute this tile (validated math, LDS reads)
        size_t gday = baseDay + (size_t)dslot;
        float vfl = gday < (size_t)n_days ? 1.f : 0.f;
        seg_body_lds(&lds[0][dslot][0], &lds[1][dslot][0], &lds[2][dslot][0],
                     seg, vfl, o, mg, tl, sh);
        __syncthreads();   // protect LDS before next tile's overwrite
    }

    // ---- block reduction: wave shuffle then LDS across the 4 waves
    #pragma unroll
    for (int off = 32; off > 0; off >>= 1) {
        o  += __shfl_down(o,  off);
        mg += __shfl_down(mg, off);
        tl += __shfl_down(tl, off);
        sh += __shfl_down(sh, off);
    }
    __shared__ float4 red[4];
    int wid = threadIdx.x >> 6;
    if ((threadIdx.x & 63) == 0) red[wid] = make_float4(o, mg, tl, sh);
    __syncthreads();
    if (threadIdx.x == 0) {
        float4 r0 = red[0], r1 = red[1], r2 = red[2], r3 = red[3];
        partials[blockIdx.x] = make_float4(r0.x + r1.x + r2.x + r3.x,
                                           r0.y + r1.y + r2.y + r3.y,
                                           r0.z + r1.z + r2.z + r3.z,
                                           r0.w + r1.w + r2.w + r3.w);
    }
}

__global__ __launch_bounds__(256) void splloss_final(
    const float4* __restrict__ partials, int nb, float* __restrict__ out,
    double inv_bs, double inv_bd, double inv_shape)
{
    double o = 0.0, m = 0.0, t = 0.0, s = 0.0;
    for (int i = threadIdx.x; i < nb; i += 256) {
        float4 p = partials[i];
        o += (double)p.x; m += (double)p.y; t += (double)p.z; s += (double)p.w;
    }
    #pragma unroll
    for (int off = 32; off > 0; off >>= 1) {
        o += __shfl_down(o, off);
        m += __shfl_down(m, off);
        t += __shfl_down(t, off);
        s += __shfl_down(s, off);
    }
    __shared__ double red[4][4];
    int wid = threadIdx.x >> 6;
    if ((threadIdx.x & 63) == 0) { red[wid][0] = o; red[wid][1] = m; red[wid][2] = t; red[wid][3] = s; }
    __syncthreads();
    if (threadIdx.x == 0) {
        double ot = red[0][0] + red[1][0] + red[2][0] + red[3][0];
        double mt = red[0][1] + red[1][1] + red[2][1] + red[3][1];
        double tt = red[0][2] + red[1][2] + red[2][2] + red[3][2];
        double st = red[0][3] + red[1][3] + red[2][3] + red[3][3];
        double total = 1.0 * (ot * inv_bs)
                     + 2.0 * (mt * inv_bd)
                     + 1.0 * (tt * inv_bd)
                     + 0.5 * (st * inv_shape);
        out[0] = (float)total;
    }
}

extern "C" void kernel_launch(void* const* d_in, const int* in_sizes, int n_in,
                              void* d_out, int out_size, void* d_ws, size_t ws_size,
                              hipStream_t stream) {
    const float* yp = (const float*)d_in[0];
    const float* yt = (const float*)d_in[1];
    const float* dm = (const float*)d_in[2];
    float* out = (float*)d_out;

    int n = in_sizes[0];              // B*S; S divisible by 24
    int n_days = n / HOURS_;          // B*D
    int ntiles = (n_days + DPB - 1) / DPB;   // 15360 at bench shape

    // 1536 persistent blocks (6/CU, LDS-limited); bench shape -> 10 tiles/block
    int nb = ntiles < 1536 ? ntiles : 1536;

    float4* partials = (float4*)d_ws; // nb * 16 bytes

    splloss_days<<<nb, 256, 0, stream>>>(yp, yt, dm, partials, n_days, ntiles);

    double inv_bs    = 1.0 / (double)n;
    double inv_bd    = 1.0 / (double)n_days;
    double inv_shape = 1.0 / ((double)n_days + 1e-6);
    splloss_final<<<1, 256, 0, stream>>>(partials, nb, out, inv_bs, inv_bd, inv_shape);
}